// Round 14
// baseline (70.092 us; speedup 1.0000x reference)
//
#include <hip/hip_runtime.h>

using bf16x8 = __attribute__((ext_vector_type(8))) short;
using u16x8  = __attribute__((ext_vector_type(8))) unsigned short;
using u32x4  = __attribute__((ext_vector_type(4))) unsigned;
using f32x4  = __attribute__((ext_vector_type(4))) float;

static constexpr int S  = 2048;
static constexpr int D  = 64;
static constexpr int TQ = 64;
static constexpr float QSCALE = 0.18033688f; // log2(e)/8 : exp2(dot) == exp(dot/8)

// HW packed f32->bf16 convert, RNE (v_cvt_pk_bf16_f32)
__device__ __forceinline__ unsigned cvtpk(float lo, float hi) {
    unsigned r;
    asm("v_cvt_pk_bf16_f32 %0, %1, %2" : "=v"(r) : "v"(lo), "v"(hi));
    return r;
}
__device__ __forceinline__ f32x4 mfma16(bf16x8 a, bf16x8 b, f32x4 c) {
    return __builtin_amdgcn_mfma_f32_16x16x32_bf16(a, b, c, 0, 0, 0);
}
// LDS-visibility barrier only: does NOT drain vmcnt
__device__ __forceinline__ void lbar() {
    asm volatile("s_waitcnt lgkmcnt(0)" ::: "memory");
    __builtin_amdgcn_s_barrier();
    asm volatile("" ::: "memory");
}
// async global->LDS DMA, 16B/lane; dest = wave-uniform base + lane*16
__device__ __forceinline__ void glds16(const void* g, void* l) {
    __builtin_amdgcn_global_load_lds(
        (const __attribute__((address_space(1))) unsigned int*)g,
        (__attribute__((address_space(3))) unsigned int*)l, 16, 0, 0);
}
#define WV0 asm volatile("s_waitcnt vmcnt(0)" ::: "memory")
#define WV2 asm volatile("s_waitcnt vmcnt(2)" ::: "memory")
#define WV4 asm volatile("s_waitcnt vmcnt(4)" ::: "memory")
#define WV6 asm volatile("s_waitcnt vmcnt(6)" ::: "memory")

// ---------------- prologue: K fp32 -> bf16, pre-swizzled per-chunk LDS image ----------------
// chunk c = K rows [16c,16c+16); layout: short off = row*64 + (gg^(row&7))*8 holds
// source cols [8gg, 8gg+8) of that row (matches main kernel's XOR-swizzled reads).
__global__ __launch_bounds__(256)
void conv_k(const float* __restrict__ K, unsigned short* __restrict__ ws)
{
    const int cid  = blockIdx.x * 4 + (threadIdx.x >> 6);
    const int lane = threadIdx.x & 63;
    const float4* src = reinterpret_cast<const float4*>(K + (size_t)cid * 1024 + lane * 16);
    const float4 f0 = src[0], f1 = src[1], f2 = src[2], f3 = src[3];
    u32x4 w0, w1;
    w0[0] = cvtpk(f0.x, f0.y); w0[1] = cvtpk(f0.z, f0.w);
    w0[2] = cvtpk(f1.x, f1.y); w0[3] = cvtpk(f1.z, f1.w);
    w1[0] = cvtpk(f2.x, f2.y); w1[1] = cvtpk(f2.z, f2.w);
    w1[2] = cvtpk(f3.x, f3.y); w1[3] = cvtpk(f3.z, f3.w);
    const int row = lane >> 2, s = row & 7, a = lane & 3;
    unsigned short* dst = ws + (size_t)cid * 1024;
    *reinterpret_cast<u32x4*>(&dst[row * 64 + ((2 * a)     ^ s) * 8]) = w0;
    *reinterpret_cast<u32x4*>(&dst[row * 64 + ((2 * a + 1) ^ s) * 8]) = w1;
}

// ---------------- main: decoupled waves, K via global_load_lds from pre-swizzled ws ----------------
__global__ __launch_bounds__(256, 2)
void monotonic_attn_glds(const float* __restrict__ Qg,
                         const unsigned short* __restrict__ ws,
                         float* __restrict__ out)
{
    __shared__ unsigned short qlds[4096];        // Q bf16 (scaled), XOR-swizzled
    __shared__ unsigned short kls[4][2][1024];   // per-wave dbuf: 16 rows x 64 bf16
    __shared__ float red[4][64];

    const int bid  = blockIdx.x;
    const int xcd  = bid & 7;
    const int m    = bid >> 3;                   // dispatch order within XCD
    const int bloc = (m < 32) ? 0 : 1;
    const int qt   = (m < 32) ? (31 - m) : (m - 32);
    const int b    = 2 * xcd + bloc;

    const int tid = threadIdx.x, lane = tid & 63, wv = tid >> 6;  // wv 0..3
    const int l15 = lane & 15, g = lane >> 4;

    const float* __restrict__ Qb = Qg + (size_t)b * S * D;
    const unsigned short* __restrict__ wsb = ws + (size_t)b * 131072;  // 128 chunks x 1024
    float* __restrict__ outb = out + (size_t)b * (size_t)S * S;

    const int q0   = qt * TQ;
    const int kend = q0 + TQ;
    const int nC   = kend >> 4;
    const int ni   = (nC - wv + 3) >> 2;

    const int roff0 = l15 * 64 + ((g    ) ^ (l15 & 7)) * 8;
    const int roff1 = l15 * 64 + ((4 | g) ^ (l15 & 7)) * 8;

    // ---------------- stage Q (scaled, bf16 via cvt_pk, XOR-swizzled) ----------------
    {
        const int qrow = tid >> 2, qc = tid & 3;
        const float4* src = reinterpret_cast<const float4*>(Qb + (size_t)(q0 + qrow) * D + qc * 16);
        float v[16];
        *reinterpret_cast<float4*>(&v[0])  = src[0];
        *reinterpret_cast<float4*>(&v[4])  = src[1];
        *reinterpret_cast<float4*>(&v[8])  = src[2];
        *reinterpret_cast<float4*>(&v[12]) = src[3];
        #pragma unroll
        for (int j = 0; j < 2; ++j) {
            u32x4 w;
            #pragma unroll
            for (int p = 0; p < 4; ++p)
                w[p] = cvtpk(v[8 * j + 2 * p] * QSCALE, v[8 * j + 2 * p + 1] * QSCALE);
            const int chunk = qc * 2 + j;
            const int off = qrow * 64 + (chunk ^ (qrow & 7)) * 8;
            *reinterpret_cast<u32x4*>(&qlds[off]) = w;
        }
    }
    lbar();

    bf16x8 qf[4][2];
    #pragma unroll
    for (int qs = 0; qs < 4; ++qs) {
        const int row = qs * 16 + l15;
        #pragma unroll
        for (int c = 0; c < 2; ++c) {
            const int off = row * 64 + ((((c << 2) | g)) ^ (row & 7)) * 8;
            qf[qs][c] = *reinterpret_cast<const bf16x8*>(&qlds[off]);
        }
    }

    auto glds_chunk = [&](int i) {               // 2 vmem ops
        const unsigned short* gsrc = wsb + (size_t)(wv + 4 * i) * 1024 + lane * 8;
        unsigned short* ldst = &kls[wv][i & 1][0];
        glds16(gsrc, ldst);
        glds16(gsrc + 512, ldst + 512);
    };

    // ---------------- pass A: row sums of exp ----------------
    float rsum[4] = {0.f, 0.f, 0.f, 0.f};
    glds_chunk(0);
    for (int i = 0; i < ni; ++i) {
        const bool more = (i + 1 < ni);
        if (more) { glds_chunk(i + 1); WV2; } else { WV0; }
        const unsigned short* bp = &kls[wv][i & 1][0];
        const bf16x8 kf0 = *reinterpret_cast<const bf16x8*>(&bp[roff0]);
        const bf16x8 kf1 = *reinterpret_cast<const bf16x8*>(&bp[roff1]);
        const int klo = (wv + 4 * i) << 4;
        const int kb  = klo + g * 4;
        #pragma unroll
        for (int qs = 0; qs < 4; ++qs) {
            const int qmin = q0 + qs * 16, qg = qmin + l15;
            if (klo > qmin + 15) continue;
            f32x4 acc = {0.f, 0.f, 0.f, 0.f};
            acc = mfma16(kf0, qf[qs][0], acc);
            acc = mfma16(kf1, qf[qs][1], acc);
            if (klo + 15 <= qmin) {
                rsum[qs] += exp2f(acc[0]) + exp2f(acc[1]) + exp2f(acc[2]) + exp2f(acc[3]);
            } else {
                #pragma unroll
                for (int r = 0; r < 4; ++r)
                    rsum[qs] += (kb + r <= qg) ? exp2f(acc[r]) : 0.f;
            }
        }
    }
    #pragma unroll
    for (int qs = 0; qs < 4; ++qs) {
        float v = rsum[qs];
        v += __shfl_xor(v, 16);
        v += __shfl_xor(v, 32);
        if (g == 0) red[wv][qs * 16 + l15] = v;
    }
    lbar();
    float inv4[4];
    #pragma unroll
    for (int qs = 0; qs < 4; ++qs) {
        const int qi = qs * 16 + l15;
        inv4[qs] = 1.f / (red[0][qi] + red[1][qi] + red[2][qi] + red[3][qi]);
    }

    // ---------------- pass B: recompute, normalize, store ----------------
    glds_chunk(0);
    for (int i = 0; i < ni; ++i) {
        const bool more = (i + 1 < ni);
        if (more) glds_chunk(i + 1);
        if (i == 0) { if (more) { WV2; } else { WV0; } }
        else        { if (more) { WV6; } else { WV4; } }
        const unsigned short* bp = &kls[wv][i & 1][0];
        const bf16x8 kf0 = *reinterpret_cast<const bf16x8*>(&bp[roff0]);
        const bf16x8 kf1 = *reinterpret_cast<const bf16x8*>(&bp[roff1]);
        const int klo = (wv + 4 * i) << 4;
        const int kb  = klo + g * 4;
        #pragma unroll
        for (int qs = 0; qs < 4; ++qs) {           // exactly 4 stores per iteration
            const int qmin = q0 + qs * 16, qg = qmin + l15;
            f32x4 ov = {0.f, 0.f, 0.f, 0.f};
            if (klo <= qmin + 15) {
                f32x4 acc = {0.f, 0.f, 0.f, 0.f};
                acc = mfma16(kf0, qf[qs][0], acc);
                acc = mfma16(kf1, qf[qs][1], acc);
                if (klo + 15 <= qmin) {
                    ov[0] = exp2f(acc[0]) * inv4[qs];
                    ov[1] = exp2f(acc[1]) * inv4[qs];
                    ov[2] = exp2f(acc[2]) * inv4[qs];
                    ov[3] = exp2f(acc[3]) * inv4[qs];
                } else {
                    ov[0] = (kb + 0 <= qg) ? exp2f(acc[0]) * inv4[qs] : 0.f;
                    ov[1] = (kb + 1 <= qg) ? exp2f(acc[1]) * inv4[qs] : 0.f;
                    ov[2] = (kb + 2 <= qg) ? exp2f(acc[2]) * inv4[qs] : 0.f;
                    ov[3] = (kb + 3 <= qg) ? exp2f(acc[3]) * inv4[qs] : 0.f;
                }
            }
            *reinterpret_cast<f32x4*>(outb + (size_t)qg * S + kb) = ov;
        }
    }

    // ---------------- zero-fill columns >= kend ----------------
    {
        f32x4 z = {0.f, 0.f, 0.f, 0.f};
        const size_t rb = (size_t)(q0 + (tid >> 2)) * S;
        for (int cc = kend + (tid & 3) * 4; cc < S; cc += 16)
            *reinterpret_cast<f32x4*>(&outb[rb + cc]) = z;
    }
}

// ---------------- fallback (round-13 kernel, used if ws too small) ----------------
__global__ __launch_bounds__(256, 2)
void monotonic_attn_fb(const float* __restrict__ Qg, const float* __restrict__ Kg,
                       float* __restrict__ out)
{
    __shared__ unsigned short qlds[4096];
    __shared__ unsigned short kls[4][2][1024];
    __shared__ float red[4][64];

    const int bid  = blockIdx.x;
    const int xcd  = bid & 7;
    const int m    = bid >> 3;
    const int bloc = (m < 32) ? 0 : 1;
    const int qt   = (m < 32) ? (31 - m) : (m - 32);
    const int b    = 2 * xcd + bloc;

    const int tid = threadIdx.x, lane = tid & 63, wv = tid >> 6;
    const int l15 = lane & 15, g = lane >> 4;

    const float* __restrict__ Qb = Qg + (size_t)b * S * D;
    const float* __restrict__ Kb = Kg + (size_t)b * S * D;
    float* __restrict__ outb = out + (size_t)b * (size_t)S * S;

    const int q0   = qt * TQ;
    const int kend = q0 + TQ;
    const int nC   = kend >> 4;
    const int ni   = (nC - wv + 3) >> 2;

    const int srow  = lane >> 2;
    const int scp   = lane & 3;
    const int woff0 = srow * 64 + (((scp << 1)    ) ^ (srow & 7)) * 8;
    const int woff1 = srow * 64 + (((scp << 1) | 1) ^ (srow & 7)) * 8;
    const int roff0 = l15 * 64 + ((g    ) ^ (l15 & 7)) * 8;
    const int roff1 = l15 * 64 + ((4 | g) ^ (l15 & 7)) * 8;

    {
        const int qrow = tid >> 2, qc = tid & 3;
        const float4* src = reinterpret_cast<const float4*>(Qb + (size_t)(q0 + qrow) * D + qc * 16);
        float v[16];
        *reinterpret_cast<float4*>(&v[0])  = src[0];
        *reinterpret_cast<float4*>(&v[4])  = src[1];
        *reinterpret_cast<float4*>(&v[8])  = src[2];
        *reinterpret_cast<float4*>(&v[12]) = src[3];
        #pragma unroll
        for (int j = 0; j < 2; ++j) {
            u32x4 w;
            #pragma unroll
            for (int p = 0; p < 4; ++p)
                w[p] = cvtpk(v[8 * j + 2 * p] * QSCALE, v[8 * j + 2 * p + 1] * QSCALE);
            const int chunk = qc * 2 + j;
            const int off = qrow * 64 + (chunk ^ (qrow & 7)) * 8;
            *reinterpret_cast<u32x4*>(&qlds[off]) = w;
        }
    }
    lbar();

    bf16x8 qf[4][2];
    #pragma unroll
    for (int qs = 0; qs < 4; ++qs) {
        const int row = qs * 16 + l15;
        #pragma unroll
        for (int c = 0; c < 2; ++c) {
            const int off = row * 64 + ((((c << 2) | g)) ^ (row & 7)) * 8;
            qf[qs][c] = *reinterpret_cast<const bf16x8*>(&qlds[off]);
        }
    }

    float inv4[4];
    for (int pass = 0; pass < 2; ++pass) {
        float rsum[4] = {0.f, 0.f, 0.f, 0.f};
        float4 ra0, ra1, ra2, ra3, rb0, rb1, rb2, rb3;
        auto issueA = [&](int i) {
            const float4* p4 = reinterpret_cast<const float4*>(Kb) + ((wv + 4 * i) << 8) + (lane << 2);
            ra0 = p4[0]; ra1 = p4[1]; ra2 = p4[2]; ra3 = p4[3];
        };
        auto issueB = [&](int i) {
            const float4* p4 = reinterpret_cast<const float4*>(Kb) + ((wv + 4 * i) << 8) + (lane << 2);
            rb0 = p4[0]; rb1 = p4[1]; rb2 = p4[2]; rb3 = p4[3];
        };
        auto stage = [&](int i, const float4& x0, const float4& x1,
                         const float4& x2, const float4& x3) {
            u32x4 w0, w1;
            w0[0] = cvtpk(x0.x, x0.y); w0[1] = cvtpk(x0.z, x0.w);
            w0[2] = cvtpk(x1.x, x1.y); w0[3] = cvtpk(x1.z, x1.w);
            w1[0] = cvtpk(x2.x, x2.y); w1[1] = cvtpk(x2.z, x2.w);
            w1[2] = cvtpk(x3.x, x3.y); w1[3] = cvtpk(x3.z, x3.w);
            unsigned short* bp = &kls[wv][i & 1][0];
            *reinterpret_cast<u32x4*>(&bp[woff0]) = w0;
            *reinterpret_cast<u32x4*>(&bp[woff1]) = w1;
        };
        auto comp = [&](int i) {
            const unsigned short* bp = &kls[wv][i & 1][0];
            const bf16x8 kf0 = *reinterpret_cast<const bf16x8*>(&bp[roff0]);
            const bf16x8 kf1 = *reinterpret_cast<const bf16x8*>(&bp[roff1]);
            const int klo = (wv + 4 * i) << 4;
            const int kb  = klo + g * 4;
            #pragma unroll
            for (int qs = 0; qs < 4; ++qs) {
                const int qmin = q0 + qs * 16, qg = qmin + l15;
                if (pass == 0) {
                    if (klo > qmin + 15) continue;
                    f32x4 acc = {0.f, 0.f, 0.f, 0.f};
                    acc = mfma16(kf0, qf[qs][0], acc);
                    acc = mfma16(kf1, qf[qs][1], acc);
                    if (klo + 15 <= qmin) {
                        rsum[qs] += exp2f(acc[0]) + exp2f(acc[1]) + exp2f(acc[2]) + exp2f(acc[3]);
                    } else {
                        #pragma unroll
                        for (int r = 0; r < 4; ++r)
                            rsum[qs] += (kb + r <= qg) ? exp2f(acc[r]) : 0.f;
                    }
                } else {
                    f32x4 ov = {0.f, 0.f, 0.f, 0.f};
                    if (klo <= qmin + 15) {
                        f32x4 acc = {0.f, 0.f, 0.f, 0.f};
                        acc = mfma16(kf0, qf[qs][0], acc);
                        acc = mfma16(kf1, qf[qs][1], acc);
                        if (klo + 15 <= qmin) {
                            ov[0] = exp2f(acc[0]) * inv4[qs];
                            ov[1] = exp2f(acc[1]) * inv4[qs];
                            ov[2] = exp2f(acc[2]) * inv4[qs];
                            ov[3] = exp2f(acc[3]) * inv4[qs];
                        } else {
                            ov[0] = (kb + 0 <= qg) ? exp2f(acc[0]) * inv4[qs] : 0.f;
                            ov[1] = (kb + 1 <= qg) ? exp2f(acc[1]) * inv4[qs] : 0.f;
                            ov[2] = (kb + 2 <= qg) ? exp2f(acc[2]) * inv4[qs] : 0.f;
                            ov[3] = (kb + 3 <= qg) ? exp2f(acc[3]) * inv4[qs] : 0.f;
                        }
                    }
                    *reinterpret_cast<f32x4*>(outb + (size_t)qg * S + kb) = ov;
                }
            }
        };

        if (ni > 0) issueA(0);
        if (ni > 1) issueB(1);
        int i = 0;
        for (; i + 2 <= ni; i += 2) {
            stage(i, ra0, ra1, ra2, ra3);
            if (i + 2 < ni) issueA(i + 2);
            comp(i);
            stage(i + 1, rb0, rb1, rb2, rb3);
            if (i + 3 < ni) issueB(i + 3);
            comp(i + 1);
        }
        if (i < ni) { stage(i, ra0, ra1, ra2, ra3); comp(i); }

        if (pass == 0) {
            #pragma unroll
            for (int qs = 0; qs < 4; ++qs) {
                float v = rsum[qs];
                v += __shfl_xor(v, 16);
                v += __shfl_xor(v, 32);
                if (g == 0) red[wv][qs * 16 + l15] = v;
            }
            lbar();
            #pragma unroll
            for (int qs = 0; qs < 4; ++qs) {
                const int qi = qs * 16 + l15;
                inv4[qs] = 1.f / (red[0][qi] + red[1][qi] + red[2][qi] + red[3][qi]);
            }
        }
    }

    {
        f32x4 z = {0.f, 0.f, 0.f, 0.f};
        const size_t rb = (size_t)(q0 + (tid >> 2)) * S;
        for (int cc = kend + (tid & 3) * 4; cc < S; cc += 16)
            *reinterpret_cast<f32x4*>(&outb[rb + cc]) = z;
    }
}

extern "C" void kernel_launch(void* const* d_in, const int* in_sizes, int n_in,
                              void* d_out, int out_size, void* d_ws, size_t ws_size,
                              hipStream_t stream)
{
    const float* Q = (const float*)d_in[0];
    const float* K = (const float*)d_in[1];
    float* out     = (float*)d_out;
    const int nb   = in_sizes[0] / (S * D);   // 16 batches

    const size_t ws_need = (size_t)nb * 128 * 1024 * sizeof(unsigned short);  // 4 MB
    if (d_ws != nullptr && ws_size >= ws_need) {
        unsigned short* ws = (unsigned short*)d_ws;
        conv_k<<<dim3(nb * 32), dim3(256), 0, stream>>>(K, ws);
        monotonic_attn_glds<<<dim3(nb * 32), dim3(256), 0, stream>>>(Q, ws, out);
    } else {
        monotonic_attn_fb<<<dim3(nb * 32), dim3(256), 0, stream>>>(Q, K, out);
    }
}